// Round 12
// baseline (85.587 us; speedup 1.0000x reference)
//
#include <hip/hip_runtime.h>

#define HID 1024
#define BATCH 256
#define KTASK 4096
#define TPB 8                 // tasks per block (2 groups of 4)
#define HK 512                // K-half
#define NROW 32               // rows per unit = 4 tasks * 8
#define RSTR 1024             // LDS row stride bytes (512 bf16, XOR-swizzled)
#define BUFB (NROW * RSTR)    // 32 KB per buffer

typedef __bf16 bf16x8 __attribute__((ext_vector_type(8)));
typedef __bf16 bf16x4 __attribute__((ext_vector_type(4)));
typedef float f32x4 __attribute__((ext_vector_type(4)));

#define MFMA(a, b, c) __builtin_amdgcn_mfma_f32_16x16x32_bf16((a), (b), (c), 0, 0, 0)

__global__ __launch_bounds__(256, 4)
void cvt_emb_kernel(const float* __restrict__ emb, __bf16* __restrict__ dst) {
    int i = (blockIdx.x * 256 + threadIdx.x) * 4;
    float4 v = *(const float4*)(emb + i);
    bf16x4 r;
    r[0] = (__bf16)v.x; r[1] = (__bf16)v.y; r[2] = (__bf16)v.z; r[3] = (__bf16)v.w;
    *(bf16x4*)(dst + i) = r;
}

// 512 blocks (all resident, 2/CU) x 512 thr. 4 units/block = 2 task-groups x
// 2 K-halves; 64 KB HBM per unit fetched row-contiguously, double-buffered
// 32 KB LDS. Block self-paces on its own in-flight W loads -> HBM never idle.
__global__ __launch_bounds__(512, 4)
void mtc_kernel(const __bf16* __restrict__ embb, const float* __restrict__ W1,
                const float* __restrict__ b1, const float* __restrict__ W2,
                const float* __restrict__ b2, const int* __restrict__ tids,
                float* __restrict__ out)
{
    __shared__ __align__(16) char wlds[2][BUFB];   // 64 KB

    const int t = threadIdx.x;
    const int lane = t & 63;
    const int w = t >> 6;                // 0..7
    const int blk = blockIdx.x;          // 0..511

    int tk[TPB];
#pragma unroll
    for (int i = 0; i < TPB; ++i) tk[i] = tids[blk * TPB + i];

    float4 v[8];                         // staging registers: 64 KB / 512 thr

    // f = t + j*512 in [0,4096): row = f>>7 (0..31), tl = f>>10, float4-in-half = f&127
#define ISSUE(tg, kh)                                                                   \
    {                                                                                   \
        _Pragma("unroll")                                                               \
        for (int j = 0; j < 8; ++j) {                                                   \
            const int f = t + j * 512;                                                  \
            const float* p = W1 + (size_t)tk[(tg) * 4 + (f >> 10)] * (8 * HID)          \
                           + (size_t)((f >> 7) & 7) * HID + (kh) * HK + (f & 127) * 4;  \
            v[j] = *(const float4*)p;                                                   \
        }                                                                               \
    }

#define WRITE(kh)                                                                       \
    {                                                                                   \
        _Pragma("unroll")                                                               \
        for (int j = 0; j < 8; ++j) {                                                   \
            const int f = t + j * 512;                                                  \
            const int row = f >> 7;                                                     \
            const int byt = ((f & 127) * 8) ^ ((row & 7) << 4);                         \
            bf16x4 r;                                                                   \
            r[0] = (__bf16)v[j].x; r[1] = (__bf16)v[j].y;                               \
            r[2] = (__bf16)v[j].z; r[3] = (__bf16)v[j].w;                               \
            *(bf16x4*)(&wlds[kh][0] + row * RSTR + byt) = r;                            \
        }                                                                               \
    }

    f32x4 acc[2][2];
    const int xorc = (lane & 7) << 4;
    const int lg16 = (lane >> 4) * 16;
    const char* const bq0 = (const char*)&wlds[0][0] + (lane & 15) * RSTR;
    const char* const bq1 = (const char*)&wlds[1][0] + (lane & 15) * RSTR;

    // k-loop over one unit: B from wlds[kh], A bf16 from L2 (4-deep ring)
#define COMPUTE(tg, kh, ZERO)                                                           \
    {                                                                                   \
        if (ZERO) {                                                                     \
            const f32x4 z = {0.f, 0.f, 0.f, 0.f};                                       \
            acc[0][0] = z; acc[0][1] = z; acc[1][0] = z; acc[1][1] = z;                  \
        }                                                                               \
        const __bf16* ag = embb + (size_t)(w * 32 + (lane & 15)) * HID                  \
                         + (kh) * HK + (lane >> 4) * 8;                                 \
        const char* bp0 = (kh) ? bq1 : bq0;                                             \
        const char* bp1 = bp0 + 16 * RSTR;                                              \
        bf16x8 ar[4][2];                                                                \
        _Pragma("unroll")                                                               \
        for (int s = 0; s < 4; ++s) {                                                   \
            ar[s][0] = *(const bf16x8*)(ag + s * 32);                                   \
            ar[s][1] = *(const bf16x8*)(ag + s * 32 + 16 * HID);                        \
        }                                                                               \
        _Pragma("unroll")                                                               \
        for (int s = 0; s < 16; ++s) {                                                  \
            const int sl = s & 3;                                                       \
            const int off = (s * 64 + lg16) ^ xorc;                                     \
            bf16x8 b0 = *(const bf16x8*)(bp0 + off);                                    \
            bf16x8 b1 = *(const bf16x8*)(bp1 + off);                                    \
            acc[0][0] = MFMA(ar[sl][0], b0, acc[0][0]);                                 \
            acc[0][1] = MFMA(ar[sl][0], b1, acc[0][1]);                                 \
            acc[1][0] = MFMA(ar[sl][1], b0, acc[1][0]);                                 \
            acc[1][1] = MFMA(ar[sl][1], b1, acc[1][1]);                                 \
            if (s + 4 < 16) {                                                           \
                ar[sl][0] = *(const bf16x8*)(ag + (s + 4) * 32);                        \
                ar[sl][1] = *(const bf16x8*)(ag + (s + 4) * 32 + 16 * HID);             \
            }                                                                           \
        }                                                                               \
    }

#define EPILOGUE(tg)                                                                    \
    {                                                                                   \
        const int col = lane & 15;                                                      \
        const int rgrp = lane >> 4;                                                     \
        const int o = col & 7;                                                          \
        _Pragma("unroll")                                                               \
        for (int nt = 0; nt < 2; ++nt) {                                                \
            const int tl = nt * 2 + (col >> 3);                                         \
            const int task = tk[(tg) * 4 + tl];                                         \
            const float bb1 = b1[task * 8 + o];                                         \
            const float ww2 = W2[task * 8 + o];                                         \
            _Pragma("unroll")                                                           \
            for (int mt = 0; mt < 2; ++mt) {                                            \
                float vv[4];                                                            \
                _Pragma("unroll")                                                       \
                for (int r = 0; r < 4; ++r) {                                           \
                    float x = acc[mt][nt][r] + bb1;                                     \
                    x = x > 0.f ? x : 0.f;                                              \
                    vv[r] = x * ww2;                                                    \
                }                                                                       \
                _Pragma("unroll")                                                       \
                for (int m = 1; m <= 4; m <<= 1) {                                      \
                    _Pragma("unroll")                                                   \
                    for (int r = 0; r < 4; ++r) vv[r] += __shfl_xor(vv[r], m, 64);      \
                }                                                                       \
                if ((lane & 7) == 0) {                                                  \
                    const float bb2 = b2[task];                                         \
                    const int brow = w * 32 + mt * 16 + rgrp * 4;                       \
                    float4 o4 = make_float4(vv[0] + bb2, vv[1] + bb2,                   \
                                            vv[2] + bb2, vv[3] + bb2);                  \
                    *(float4*)(out + (size_t)(blk * TPB + (tg) * 4 + tl) * BATCH        \
                               + brow) = o4;                                            \
                }                                                                       \
            }                                                                           \
        }                                                                               \
    }

    // ---------------- 4-unit pipeline ----------------
    ISSUE(0, 0);
    // u0: (tg0, lo) -> buf0
    WRITE(0); __syncthreads(); ISSUE(0, 1); COMPUTE(0, 0, 1);
    // u1: (tg0, hi) -> buf1
    WRITE(1); __syncthreads(); ISSUE(1, 0); COMPUTE(0, 1, 0); EPILOGUE(0);
    // u2: (tg1, lo) -> buf0
    WRITE(0); __syncthreads(); ISSUE(1, 1); COMPUTE(1, 0, 1);
    // u3: (tg1, hi) -> buf1
    WRITE(1); __syncthreads(); COMPUTE(1, 1, 0); EPILOGUE(1);

#undef ISSUE
#undef WRITE
#undef COMPUTE
#undef EPILOGUE
}

extern "C" void kernel_launch(void* const* d_in, const int* in_sizes, int n_in,
                              void* d_out, int out_size, void* d_ws, size_t ws_size,
                              hipStream_t stream) {
    const float* emb = (const float*)d_in[0];
    const float* W1  = (const float*)d_in[1];
    const float* b1  = (const float*)d_in[2];
    const float* W2  = (const float*)d_in[3];
    const float* b2  = (const float*)d_in[4];
    const int*   tid = (const int*)d_in[5];
    float* outp = (float*)d_out;
    __bf16* embb = (__bf16*)d_ws;   // 512 KB

    cvt_emb_kernel<<<dim3(BATCH * HID / (256 * 4)), dim3(256), 0, stream>>>(emb, embb);
    mtc_kernel<<<dim3(KTASK / TPB), dim3(512), 0, stream>>>(embb, W1, b1, W2, b2, tid, outp);
}